// Round 15
// baseline (169.379 us; speedup 1.0000x reference)
//
#include <hip/hip_runtime.h>

#define NN 50000
#define NE 1600000
#define NT (NE + NN)   // total edges incl self loops
#define NF 512
#define F1 128
#define NH 8
#define F2 40

#define NB 196         // dst buckets of 256 nodes
#define BCAP 10240     // per-bucket staging capacity (mean 8163, sd ~90)
#define TILE 4096

#define NB_PREP 70     // wprep blocks in k_prep
#define NB_BINA ((NE + TILE - 1) / TILE)   // 391
#define NB_G1 ((NN + 31) / 32)             // 1563

typedef __attribute__((ext_vector_type(8))) short short8;
typedef __attribute__((ext_vector_type(4))) short short4v;
typedef __attribute__((ext_vector_type(4))) float f32x4;
typedef __attribute__((ext_vector_type(2))) float f32x2;

__device__ __forceinline__ float lrelu(float x) { return fmaxf(x, 0.2f * x); }

__device__ __forceinline__ unsigned short f2bf(float f) {
  unsigned int u = __float_as_uint(f);
  u += 0x7fffu + ((u >> 16) & 1u);  // RNE
  return (unsigned short)(u >> 16);
}
__device__ __forceinline__ float bfhi(unsigned int dw) { return __uint_as_float(dw & 0xffff0000u); }
__device__ __forceinline__ float bflo(unsigned int dw) { return __uint_as_float(dw << 16); }
__device__ __forceinline__ float elu(float x) { return x > 0.f ? x : __expf(x) - 1.f; }

__device__ __forceinline__ unsigned char f2fp8(float v) {
  return (unsigned char)(__builtin_amdgcn_cvt_pk_fp8_f32(v, v, 0, false) & 0xFF);
}

// ================= k_prep: wprep (blocks 0..69) || binA (blocks 70..460) =================
__global__ __launch_bounds__(256) void k_prep(const float* __restrict__ W1,
                                              const float* __restrict__ W2,
                                              unsigned short* __restrict__ W1b,
                                              unsigned short* __restrict__ W2b,
                                              const int* __restrict__ esrc,
                                              const int* __restrict__ edst,
                                              const float* __restrict__ ew,
                                              int* __restrict__ bktCnt,
                                              uint2* __restrict__ bSrcEw,
                                              unsigned short* __restrict__ bDst) {
  __shared__ __align__(16) char sm[46080];
  const int t = threadIdx.x;

  if (blockIdx.x < NB_PREP) {
    // ---- weight prepass ----
    int i = blockIdx.x * 256 + t;
    if (i < 16384) {  // W1: 16384 float4s
      float4 v = ((const float4*)W1)[i];
      short4v b;
      b[0] = (short)f2bf(v.x); b[1] = (short)f2bf(v.y);
      b[2] = (short)f2bf(v.z); b[3] = (short)f2bf(v.w);
      *(short4v*)&W1b[(size_t)i * 4] = b;
    } else if (i < 16384 + 1536) {  // W2b: 48 rows x 32 float4s (pad rows 40..47 with 0)
      int j = i - 16384;
      int col = j >> 5, q = j & 31;
      short4v b = {0, 0, 0, 0};
      if (col < 40) {
        float4 v = ((const float4*)W2)[col * 32 + q];
        b[0] = (short)f2bf(v.x); b[1] = (short)f2bf(v.y);
        b[2] = (short)f2bf(v.z); b[3] = (short)f2bf(v.w);
      }
      *(short4v*)&W2b[(size_t)col * 128 + q * 4] = b;
    }
    return;
  }

  // ---- binA: bucket-bin a 4096-edge tile ----
  int* cnt = (int*)sm;                       // 196 (pad 1024)
  int* scn = (int*)(sm + 1024);
  int* gbase = (int*)(sm + 2048);
  int* cur = (int*)(sm + 3072);
  int* tmp = (int*)(sm + 4096);              // 256
  uint2* stSE = (uint2*)(sm + 5120);         // 4096*8 = 32768
  unsigned short* stD = (unsigned short*)(sm + 37888);  // 8192
  const int e0 = (blockIdx.x - NB_PREP) * TILE;

  for (int b = t; b < NB; b += 256) cnt[b] = 0;
  __syncthreads();

  unsigned int sd[16];
  float wv[16];
#pragma unroll
  for (int u = 0; u < 16; ++u) {
    int e = e0 + t + 256 * u;
    if (e < NE) {
      unsigned int s = (unsigned int)esrc[e];
      unsigned int d = (unsigned int)edst[e];
      sd[u] = s | (d << 16);
      wv[u] = ew[e];
      atomicAdd(&cnt[d >> 8], 1);
    } else {
      sd[u] = 0xFFFFFFFFu;
    }
  }
  __syncthreads();

  int v = (t < NB) ? cnt[t] : 0;
  tmp[t] = v;
  __syncthreads();
  for (int off = 1; off < 256; off <<= 1) {
    int a = (t >= off) ? tmp[t - off] : 0;
    __syncthreads();
    tmp[t] += a;
    __syncthreads();
  }
  if (t < NB) {
    scn[t] = tmp[t] - v;
    cur[t] = tmp[t] - v;
    gbase[t] = atomicAdd(&bktCnt[t], v);
  }
  __syncthreads();

#pragma unroll
  for (int u = 0; u < 16; ++u) {
    if (sd[u] != 0xFFFFFFFFu) {
      unsigned int d = sd[u] >> 16;
      int p = atomicAdd(&cur[d >> 8], 1);
      stSE[p] = make_uint2(sd[u] & 0xFFFFu, __float_as_uint(wv[u]));
      stD[p] = (unsigned short)d;
    }
  }
  __syncthreads();

  int tot = NE - e0;
  if (tot > TILE) tot = TILE;
  for (int k = t; k < tot; k += 256) {
    int d = stD[k];
    int b = d >> 8;
    int idx = gbase[b] + (k - scn[b]);
    bSrcEw[(size_t)b * BCAP + idx] = stSE[k];
    bDst[(size_t)b * BCAP + idx] = (unsigned short)d;
  }
}

// ====== k_fuse2: fillB (blocks 0..195, inline bucket-prefix) || gemm1 (blocks 196..) ======
// gemm1: BM=32, BK=32, double-buffered LDS (25.6 KB), ONE barrier per chunk
__global__ __launch_bounds__(256) void k_fuse2(const int* __restrict__ bktCnt,
                                               const uint2* __restrict__ bSrcEw,
                                               const unsigned short* __restrict__ bDst,
                                               const float* __restrict__ ew,
                                               int* __restrict__ rs,
                                               uint2* __restrict__ edge,
                                               const float* __restrict__ x,
                                               const unsigned short* __restrict__ W1b,
                                               const float* __restrict__ attl,
                                               const float* __restrict__ attr,
                                               unsigned int* __restrict__ h1f32,
                                               float* __restrict__ al,
                                               float* __restrict__ ar) {
  __shared__ __align__(16) char sm[25600];
  const int t = threadIdx.x;

  if (blockIdx.x < NB) {
    // ---------------- fillB path ----------------
    int* cnt = (int*)sm;               // 256
    int* cur = (int*)(sm + 1024);      // 256
    int* tmp = (int*)(sm + 2048);      // 256
    int* bpre = (int*)(sm + 3072);     // 256
    int* sGb = (int*)(sm + 4096);
    const int b = blockIdx.x;
    const int n0 = b * 256;
    const int nNodes = (n0 + 256 <= NN) ? 256 : (NN - n0);

    // global bucket prefix, computed per block
    int bc = (t < NB) ? bktCnt[t] : 0;
    int nInB = 0;
    if (t < NB) nInB = (t == NB - 1) ? (NN - (NB - 1) * 256) : 256;
    int pv = bc + nInB;
    bpre[t] = pv;
    __syncthreads();
    for (int off = 1; off < 256; off <<= 1) {
      int a = (t >= off) ? bpre[t - off] : 0;
      __syncthreads();
      bpre[t] += a;
      __syncthreads();
    }
    if (t == b) *sGb = bpre[t] - pv;  // exclusive prefix at b
    if (t == 0 && b == 0) rs[NN] = NT;
    __syncthreads();
    const int gb = *sGb;
    const int cE = bktCnt[b];

    cnt[t] = 0;
    __syncthreads();
    for (int k = t; k < cE; k += 256) atomicAdd(&cnt[bDst[(size_t)b * BCAP + k] & 255], 1);
    __syncthreads();

    int v = (t < nNodes) ? cnt[t] + 1 : 0;  // +1 self loop
    tmp[t] = v;
    __syncthreads();
    for (int off = 1; off < 256; off <<= 1) {
      int a = (t >= off) ? tmp[t - off] : 0;
      __syncthreads();
      tmp[t] += a;
      __syncthreads();
    }
    int off_ = tmp[t] - v;  // exclusive
    if (t < nNodes) {
      rs[n0 + t] = gb + off_;
      cur[t] = off_ + 1;  // slot 0 = self loop
      edge[(size_t)gb + off_] = make_uint2((unsigned int)(n0 + t), __float_as_uint(ew[NE + n0 + t]));
    }
    __syncthreads();

    for (int k = t; k < cE; k += 256) {
      uint2 se = bSrcEw[(size_t)b * BCAP + k];
      int d = bDst[(size_t)b * BCAP + k] & 255;
      int p = atomicAdd(&cur[d], 1);
      edge[(size_t)gb + p] = se;  // XCD-local window
    }
    return;
  }

  // ---------------- gemm1 path: BK=32 double-buffer ----------------
  unsigned short* As0 = (unsigned short*)sm;             // 32*40*2 = 2560
  unsigned short* As1 = (unsigned short*)(sm + 2560);    // 2560
  unsigned short* Bs0 = (unsigned short*)(sm + 5120);    // 128*40*2 = 10240
  unsigned short* Bs1 = (unsigned short*)(sm + 15360);   // 10240
  unsigned int* pk32 = (unsigned int*)sm;                // overlaid on As0/As1 (post-loop only)
  const int w = t >> 6, lane = t & 63;
  const int g16 = lane >> 4, r16 = lane & 15;
  const int m0 = (blockIdx.x - NB) * 32;
  const int r0 = (w & 1) * 16;
  const int c0 = (w >> 1) * 64;
  const int arow = t >> 3, ak4 = (t & 7) << 2;   // A staging: row 0..31, k 0..28
  const int bc1 = t >> 2, bk8 = (t & 3) << 3;    // B staging: cols bc1, bc1+64; k 0..24

  const int nA = m0 + arow;
  const bool vA = nA < NN;

  float4 av;
  short8 bv0, bv1;

  // prologue: load + stage chunk 0 into buf0
  av = vA ? *(const float4*)&x[(size_t)nA * NF + ak4] : make_float4(0.f, 0.f, 0.f, 0.f);
  bv0 = *(const short8*)&W1b[(size_t)bc1 * NF + bk8];
  bv1 = *(const short8*)&W1b[(size_t)(bc1 + 64) * NF + bk8];
  {
    short4v b0;
    b0[0] = (short)f2bf(av.x); b0[1] = (short)f2bf(av.y);
    b0[2] = (short)f2bf(av.z); b0[3] = (short)f2bf(av.w);
    *(short4v*)&As0[arow * 40 + ak4] = b0;
    *(short8*)&Bs0[bc1 * 40 + bk8] = bv0;
    *(short8*)&Bs0[(bc1 + 64) * 40 + bk8] = bv1;
  }
  __syncthreads();

  f32x4 acc[4];
#pragma unroll
  for (int b = 0; b < 4; ++b) acc[b] = (f32x4){0.f, 0.f, 0.f, 0.f};

  for (int kc = 0; kc < 16; ++kc) {
    unsigned short* Ac = (kc & 1) ? As1 : As0;
    unsigned short* Bc = (kc & 1) ? Bs1 : Bs0;
    unsigned short* An = (kc & 1) ? As0 : As1;
    unsigned short* Bn = (kc & 1) ? Bs0 : Bs1;
    const bool ld = (kc < 15);

    // issue next-chunk global loads FIRST (latency spans ds_read + MFMA)
    if (ld) {
      int kn = (kc + 1) * 32;
      av = vA ? *(const float4*)&x[(size_t)nA * NF + kn + ak4] : make_float4(0.f, 0.f, 0.f, 0.f);
      bv0 = *(const short8*)&W1b[(size_t)bc1 * NF + kn + bk8];
      bv1 = *(const short8*)&W1b[(size_t)(bc1 + 64) * NF + kn + bk8];
    }

    // current-chunk fragments from LDS
    short8 afr = *(const short8*)&Ac[(r0 + r16) * 40 + g16 * 8];
    short8 bfr[4];
#pragma unroll
    for (int nj = 0; nj < 4; ++nj)
      bfr[nj] = *(const short8*)&Bc[(c0 + nj * 16 + r16) * 40 + g16 * 8];

#pragma unroll
    for (int nj = 0; nj < 4; ++nj)
      acc[nj] = __builtin_amdgcn_mfma_f32_16x16x32_bf16(afr, bfr[nj], acc[nj], 0, 0, 0);

    // write next chunk into the other buffer (safe: previous barrier ordered reads)
    if (ld) {
      short4v b0;
      b0[0] = (short)f2bf(av.x); b0[1] = (short)f2bf(av.y);
      b0[2] = (short)f2bf(av.z); b0[3] = (short)f2bf(av.w);
      *(short4v*)&An[arow * 40 + ak4] = b0;
      *(short8*)&Bn[bc1 * 40 + bk8] = bv0;
      *(short8*)&Bn[(bc1 + 64) * 40 + bk8] = bv1;
      __syncthreads();  // ONE barrier per chunk
    }
  }

  // fp8-pack into LDS (pk32 overlays As0/As1 — dead after this barrier)
  unsigned char* pkb = (unsigned char*)pk32;
  __syncthreads();
#pragma unroll
  for (int nj = 0; nj < 4; ++nj)
#pragma unroll
    for (int r = 0; r < 4; ++r)
      pkb[(r0 + g16 * 4 + r) * 128 + c0 + nj * 16 + r16] = f2fp8(acc[nj][r]);
  __syncthreads();

  {
    int row = t >> 3, q = t & 7;
    int n = m0 + row;
    if (n < NN) ((uint4*)h1f32)[(size_t)n * 8 + q] = ((const uint4*)pk32)[row * 8 + q];
  }
  {
    int row = t >> 3, h = t & 7;
    int n = m0 + row;
    if (n < NN) {
      float a = 0.f, b = 0.f;
#pragma unroll
      for (int c = 0; c < 4; ++c) {
        unsigned int u = pk32[row * 32 + h * 4 + c];
        f32x2 lo = __builtin_amdgcn_cvt_pk_f32_fp8((int)u, false);
        f32x2 hi = __builtin_amdgcn_cvt_pk_f32_fp8((int)u, true);
        int f0 = h * 16 + 4 * c;
        a = fmaf(lo[0], attl[f0], a);
        a = fmaf(lo[1], attl[f0 + 1], a);
        a = fmaf(hi[0], attl[f0 + 2], a);
        a = fmaf(hi[1], attl[f0 + 3], a);
        b = fmaf(lo[0], attr[f0], b);
        b = fmaf(lo[1], attr[f0 + 1], b);
        b = fmaf(hi[0], attr[f0 + 2], b);
        b = fmaf(hi[1], attr[f0 + 3], b);
      }
      al[n * 8 + h] = a;
      ar[n * 8 + h] = b;
    }
  }
}

// ---- layer-1 aggregation: 2 nodes/wave, 12-deep batch, plain exp, fp8 gather ----
__global__ __launch_bounds__(256) void k_agg1(const int* __restrict__ rs,
                                              const uint2* __restrict__ edge,
                                              const unsigned int* __restrict__ h1f32,
                                              const float* __restrict__ al,
                                              const float* __restrict__ ar,
                                              const float* __restrict__ b1,
                                              uint2* __restrict__ h1eb) {
  const int hl = threadIdx.x & 31;
  const int i = blockIdx.x * 8 + (threadIdx.x >> 5);
  if (i >= NN) return;
  const int base = rs[i], end = rs[i + 1];
  const int head = hl >> 2;
  const float arh = ar[i * 8 + head];
  float s0 = 0.f, s1 = 0.f;
  float a0 = 0.f, a1 = 0.f, a2 = 0.f, a3 = 0.f;
  float c0 = 0.f, c1 = 0.f, c2 = 0.f, c3 = 0.f;

  int e = base;
  for (; e + 12 <= end; e += 12) {
    uint2 ce[12];
    float lgs[12];
    unsigned int hvs[12];
#pragma unroll
    for (int u = 0; u < 12; ++u) ce[u] = edge[e + u];
#pragma unroll
    for (int u = 0; u < 12; ++u) lgs[u] = al[(int)ce[u].x * 8 + head];
#pragma unroll
    for (int u = 0; u < 12; ++u) hvs[u] = h1f32[(size_t)ce[u].x * 32 + hl];
#pragma unroll
    for (int u = 0; u < 12; ++u) {
      float q = __expf(lrelu(lgs[u] + arh));
      float pw = q * __uint_as_float(ce[u].y);
      f32x2 lo = __builtin_amdgcn_cvt_pk_f32_fp8((int)hvs[u], false);
      f32x2 hi = __builtin_amdgcn_cvt_pk_f32_fp8((int)hvs[u], true);
      if (u & 1) {
        s1 += q;
        c0 = fmaf(pw, lo[0], c0);
        c1 = fmaf(pw, lo[1], c1);
        c2 = fmaf(pw, hi[0], c2);
        c3 = fmaf(pw, hi[1], c3);
      } else {
        s0 += q;
        a0 = fmaf(pw, lo[0], a0);
        a1 = fmaf(pw, lo[1], a1);
        a2 = fmaf(pw, hi[0], a2);
        a3 = fmaf(pw, hi[1], a3);
      }
    }
  }
  for (; e + 4 <= end; e += 4) {
    uint2 ce[4];
    float lgs[4];
    unsigned int hvs[4];
#pragma unroll
    for (int u = 0; u < 4; ++u) ce[u] = edge[e + u];
#pragma unroll
    for (int u = 0; u < 4; ++u) lgs[u] = al[(int)ce[u].x * 8 + head];
#pragma unroll
    for (int u = 0; u < 4; ++u) hvs[u] = h1f32[(size_t)ce[u].x * 32 + hl];
#pragma unroll
    for (int u = 0; u < 4; ++u) {
      float q = __expf(lrelu(lgs[u] + arh));
      float pw = q * __uint_as_float(ce[u].y);
      f32x2 lo = __builtin_amdgcn_cvt_pk_f32_fp8((int)hvs[u], false);
      f32x2 hi = __builtin_amdgcn_cvt_pk_f32_fp8((int)hvs[u], true);
      if (u & 1) {
        s1 += q;
        c0 = fmaf(pw, lo[0], c0);
        c1 = fmaf(pw, lo[1], c1);
        c2 = fmaf(pw, hi[0], c2);
        c3 = fmaf(pw, hi[1], c3);
      } else {
        s0 += q;
        a0 = fmaf(pw, lo[0], a0);
        a1 = fmaf(pw, lo[1], a1);
        a2 = fmaf(pw, hi[0], a2);
        a3 = fmaf(pw, hi[1], a3);
      }
    }
  }
  for (; e < end; ++e) {
    uint2 ce = edge[e];
    int j = (int)ce.x;
    float q = __expf(lrelu(al[j * 8 + head] + arh));
    unsigned int hv = h1f32[(size_t)j * 32 + hl];
    float pw = q * __uint_as_float(ce.y);
    f32x2 lo = __builtin_amdgcn_cvt_pk_f32_fp8((int)hv, false);
    f32x2 hi = __builtin_amdgcn_cvt_pk_f32_fp8((int)hv, true);
    s0 += q;
    a0 = fmaf(pw, lo[0], a0);
    a1 = fmaf(pw, lo[1], a1);
    a2 = fmaf(pw, hi[0], a2);
    a3 = fmaf(pw, hi[1], a3);
  }
  float inv = 1.f / (s0 + s1);
  float4 bias = *(const float4*)&b1[4 * hl];
  float o0 = elu(fmaf(a0 + c0, inv, bias.x));
  float o1 = elu(fmaf(a1 + c1, inv, bias.y));
  float o2 = elu(fmaf(a2 + c2, inv, bias.z));
  float o3 = elu(fmaf(a3 + c3, inv, bias.w));
  uint2 pk;
  pk.x = (unsigned int)f2bf(o0) | ((unsigned int)f2bf(o1) << 16);
  pk.y = (unsigned int)f2bf(o2) | ((unsigned int)f2bf(o3) << 16);
  h1eb[(size_t)i * 32 + hl] = pk;
}

// ---- GEMM2 (MFMA bf16, one K-shot): hp2f[N][40] = fp8(h1e @ W2^T); fused alr2 ----
__global__ __launch_bounds__(256) void k_gemm2(const uint4* __restrict__ h1eb4,
                                               const unsigned short* __restrict__ W2b,
                                               const float* __restrict__ attl,
                                               const float* __restrict__ attr,
                                               unsigned int* __restrict__ hp2f32,
                                               float* __restrict__ al,
                                               float* __restrict__ ar) {
  __shared__ unsigned short As[64 * 136];
  __shared__ unsigned short Bs[48 * 136];
  __shared__ unsigned int pkd[64 * 10];
  const int t = threadIdx.x;
  const int w = t >> 6, lane = t & 63;
  const int g16 = lane >> 4, r16 = lane & 15;
  const int n0 = blockIdx.x * 64;

#pragma unroll
  for (int i = 0; i < 4; ++i) {
    int idx = t + 256 * i;
    int row = idx >> 4, q = idx & 15;
    int n = n0 + row;
    uint4 v = make_uint4(0u, 0u, 0u, 0u);
    if (n < NN) v = h1eb4[(size_t)n * 16 + q];
    *(uint4*)&As[row * 136 + q * 8] = v;
  }
#pragma unroll
  for (int i = 0; i < 3; ++i) {
    int idx = t + 256 * i;
    int col = idx >> 4, q = idx & 15;
    *(uint4*)&Bs[col * 136 + q * 8] = ((const uint4*)W2b)[col * 16 + q];
  }
  __syncthreads();

  f32x4 acc[3];
#pragma unroll
  for (int b = 0; b < 3; ++b) acc[b] = (f32x4){0.f, 0.f, 0.f, 0.f};
  short8 afr[4];
#pragma unroll
  for (int kc = 0; kc < 4; ++kc)
    afr[kc] = *(const short8*)&As[(w * 16 + r16) * 136 + kc * 32 + g16 * 8];
#pragma unroll
  for (int nt = 0; nt < 3; ++nt) {
#pragma unroll
    for (int kc = 0; kc < 4; ++kc) {
      short8 bfr = *(const short8*)&Bs[(nt * 16 + r16) * 136 + kc * 32 + g16 * 8];
      acc[nt] = __builtin_amdgcn_mfma_f32_16x16x32_bf16(afr[kc], bfr, acc[nt], 0, 0, 0);
    }
  }

  unsigned char* pkb = (unsigned char*)pkd;
  __syncthreads();
#pragma unroll
  for (int nt = 0; nt < 3; ++nt) {
    int col = nt * 16 + r16;
    if (col < 40) {
#pragma unroll
      for (int r = 0; r < 4; ++r)
        pkb[(w * 16 + g16 * 4 + r) * 40 + col] = f2fp8(acc[nt][r]);
    }
  }
  __syncthreads();

  for (int idx = t; idx < 640; idx += 256) {
    int row = idx / 10, q = idx - row * 10;
    int n = n0 + row;
    if (n < NN) hp2f32[(size_t)n * 10 + q] = pkd[row * 10 + q];
  }
  if (t < 64) {
    int n = n0 + t;
    if (n < NN) {
      float a = 0.f, b = 0.f;
#pragma unroll
      for (int c = 0; c < 10; ++c) {
        unsigned int u = pkd[t * 10 + c];
        f32x2 lo = __builtin_amdgcn_cvt_pk_f32_fp8((int)u, false);
        f32x2 hi = __builtin_amdgcn_cvt_pk_f32_fp8((int)u, true);
        a = fmaf(lo[0], attl[4 * c], a);
        a = fmaf(lo[1], attl[4 * c + 1], a);
        a = fmaf(hi[0], attl[4 * c + 2], a);
        a = fmaf(hi[1], attl[4 * c + 3], a);
        b = fmaf(lo[0], attr[4 * c], b);
        b = fmaf(lo[1], attr[4 * c + 1], b);
        b = fmaf(hi[0], attr[4 * c + 2], b);
        b = fmaf(hi[1], attr[4 * c + 3], b);
      }
      al[n] = a;
      ar[n] = b;
    }
  }
}

// ---- layer-2 attention prepass: 2 nodes/wave; edge.y <- q*ew, sinv[i] = 1/sum(q) ----
__global__ __launch_bounds__(256) void k_qw2(const int* __restrict__ rs,
                                             uint2* __restrict__ edge,
                                             const float* __restrict__ al2,
                                             const float* __restrict__ ar2,
                                             float* __restrict__ sinv) {
  const int l = threadIdx.x & 31;
  const int i = blockIdx.x * 8 + (threadIdx.x >> 5);
  if (i >= NN) return;
  const int base = rs[i], end = rs[i + 1];
  const float ari = ar2[i];
  float s = 0.f;
  for (int e = base + l; e < end; e += 32) {
    uint2 ce = edge[e];
    float q = __expf(lrelu(al2[(int)ce.x] + ari));
    s += q;
    ((float*)&edge[e])[1] = q * __uint_as_float(ce.y);
  }
#pragma unroll
  for (int off = 1; off < 32; off <<= 1) s += __shfl_xor(s, off, 32);
  if (l == 0) sinv[i] = 1.f / s;
}

// ---- layer-2 aggregation + bias + log_softmax: 2 nodes/wave, 16-deep batch ----
__global__ __launch_bounds__(256) void k_agg2(const int* __restrict__ rs,
                                              const uint2* __restrict__ edge,
                                              const unsigned short* __restrict__ hp2f16,
                                              const float* __restrict__ sinv,
                                              const float* __restrict__ b2,
                                              float* __restrict__ out) {
  const int hl = threadIdx.x & 31;
  const int i = blockIdx.x * 8 + (threadIdx.x >> 5);
  if (i >= NN) return;
  const int base = rs[i], end = rs[i + 1];
  float a0 = 0.f, a1 = 0.f, c0 = 0.f, c1 = 0.f;

  int e = base;
  for (; e + 16 <= end; e += 16) {
    uint2 ce[16];
#pragma unroll
    for (int u = 0; u < 16; ++u) ce[u] = edge[e + u];
    unsigned int hv[16];
#pragma unroll
    for (int u = 0; u < 16; ++u)
      hv[u] = (hl < 20) ? (unsigned int)hp2f16[(size_t)ce[u].x * 20 + hl] : 0u;
#pragma unroll
    for (int u = 0; u < 16; ++u) {
      float p = __uint_as_float(ce[u].y);
      f32x2 v = __builtin_amdgcn_cvt_pk_f32_fp8((int)hv[u], false);
      if (u & 1) {
        c0 = fmaf(p, v[0], c0);
        c1 = fmaf(p, v[1], c1);
      } else {
        a0 = fmaf(p, v[0], a0);
        a1 = fmaf(p, v[1], a1);
      }
    }
  }
  for (; e + 4 <= end; e += 4) {
    uint2 ce[4];
#pragma unroll
    for (int u = 0; u < 4; ++u) ce[u] = edge[e + u];
    unsigned int hv[4];
#pragma unroll
    for (int u = 0; u < 4; ++u)
      hv[u] = (hl < 20) ? (unsigned int)hp2f16[(size_t)ce[u].x * 20 + hl] : 0u;
#pragma unroll
    for (int u = 0; u < 4; ++u) {
      float p = __uint_as_float(ce[u].y);
      f32x2 v = __builtin_amdgcn_cvt_pk_f32_fp8((int)hv[u], false);
      if (u & 1) {
        c0 = fmaf(p, v[0], c0);
        c1 = fmaf(p, v[1], c1);
      } else {
        a0 = fmaf(p, v[0], a0);
        a1 = fmaf(p, v[1], a1);
      }
    }
  }
  for (; e < end; ++e) {
    uint2 ce = edge[e];
    unsigned int hv = (hl < 20) ? (unsigned int)hp2f16[(size_t)ce.x * 20 + hl] : 0u;
    float p = __uint_as_float(ce.y);
    f32x2 v = __builtin_amdgcn_cvt_pk_f32_fp8((int)hv, false);
    a0 = fmaf(p, v[0], a0);
    a1 = fmaf(p, v[1], a1);
  }
  a0 += c0;
  a1 += c1;
  float inv = sinv[i];
  float v0 = -1e30f, v1 = -1e30f;
  if (hl < 20) {
    v0 = fmaf(a0, inv, b2[2 * hl]);
    v1 = fmaf(a1, inv, b2[2 * hl + 1]);
  }
  float mx = fmaxf(v0, v1);
#pragma unroll
  for (int off = 1; off < 32; off <<= 1) mx = fmaxf(mx, __shfl_xor(mx, off, 32));
  float se = (hl < 20) ? __expf(v0 - mx) + __expf(v1 - mx) : 0.f;
#pragma unroll
  for (int off = 1; off < 32; off <<= 1) se += __shfl_xor(se, off, 32);
  if (hl < 20) {
    float ls = mx + __logf(se);
    ((float2*)(out + (size_t)i * 40))[hl] = make_float2(v0 - ls, v1 - ls);
  }
}

extern "C" void kernel_launch(void* const* d_in, const int* in_sizes, int n_in,
                              void* d_out, int out_size, void* d_ws, size_t ws_size,
                              hipStream_t stream) {
  const float* x     = (const float*)d_in[0];
  const int*   esrc  = (const int*)d_in[1];
  const int*   edst  = (const int*)d_in[2];
  const float* ew    = (const float*)d_in[3];
  const float* W1    = (const float*)d_in[4];
  const float* attl1 = (const float*)d_in[5];
  const float* attr1 = (const float*)d_in[6];
  const float* b1    = (const float*)d_in[7];
  const float* W2    = (const float*)d_in[8];
  const float* attl2 = (const float*)d_in[9];
  const float* attr2 = (const float*)d_in[10];
  const float* b2    = (const float*)d_in[11];
  float* out = (float*)d_out;

  char* w = (char*)d_ws;
  auto take = [&](size_t bytes) {
    char* p = w;
    w += (bytes + 255) & ~(size_t)255;
    return p;
  };
  unsigned int* h1f  = (unsigned int*)take((size_t)NN * F1);       // fp8 table, 6.4 MB
  unsigned int* h1eb = (unsigned int*)take((size_t)NN * 64 * 4);   // bf16, 12.8 MB
  float* al1 = (float*)take((size_t)NN * NH * 4);
  float* ar1 = (float*)take((size_t)NN * NH * 4);
  unsigned int* hp2f = (unsigned int*)take((size_t)NN * 40);       // fp8 table, 2 MB
  float* al2 = (float*)take((size_t)NN * 4);
  float* ar2 = (float*)take((size_t)NN * 4);
  float* sinv = (float*)take((size_t)NN * 4);
  int*   rs  = (int*)take((size_t)(NN + 1) * 4);
  uint2* edge = (uint2*)take((size_t)NT * 8);
  unsigned short* W1b = (unsigned short*)take((size_t)F1 * NF * 2); // 128 KB bf16 W1
  unsigned short* W2b = (unsigned short*)take((size_t)48 * 128 * 2); // 12 KB bf16 W2 (pad 48)
  int* bktCnt = (int*)take(NB * 4);
  // DEDICATED staging (no aliasing! fillB runs concurrently with gemm1 which writes h1f/al1)
  uint2* bSrcEw = (uint2*)take((size_t)NB * BCAP * 8);              // 16.06 MB
  unsigned short* bDst = (unsigned short*)take((size_t)NB * BCAP * 2);  // 4.01 MB

  hipMemsetAsync(bktCnt, 0, NB * 4, stream);
  // wprep || binA
  k_prep<<<NB_PREP + NB_BINA, 256, 0, stream>>>(W1, W2, W1b, W2b,
                                                esrc, edst, ew, bktCnt, bSrcEw, bDst);
  // fillB (with inline bucket scan) || gemm1(+alr1, BK=32 double-buffered)
  k_fuse2<<<NB + NB_G1, 256, 0, stream>>>(bktCnt, bSrcEw, bDst, ew, rs, edge,
                                          x, W1b, attl1, attr1, h1f, al1, ar1);
  // layer-1 aggregation
  k_agg1<<<(NN + 7) / 8, 256, 0, stream>>>(rs, edge, h1f, al1, ar1, b1, (uint2*)h1eb);
  // layer 2
  k_gemm2<<<(NN + 63) / 64, 256, 0, stream>>>((const uint4*)h1eb, W2b, attl2, attr2,
                                              hp2f, al2, ar2);
  k_qw2<<<(NN + 7) / 8, 256, 0, stream>>>(rs, edge, al2, ar2, sinv);
  k_agg2<<<(NN + 7) / 8, 256, 0, stream>>>(rs, edge, (const unsigned short*)hp2f, sinv, b2, out);
}

// Round 16
// 165.546 us; speedup vs baseline: 1.0232x; 1.0232x over previous
//
#include <hip/hip_runtime.h>

#define NN 50000
#define NE 1600000
#define NT (NE + NN)   // total edges incl self loops
#define NF 512
#define F1 128
#define NH 8
#define F2 40

#define NB 196         // dst buckets of 256 nodes
#define BCAP 10240     // per-bucket staging capacity (mean 8163, sd ~90)
#define TILE 4096

#define NB_PREP 70     // wprep blocks in k_prep
#define NB_BINA ((NE + TILE - 1) / TILE)   // 391
#define NB_G1 ((NN + 31) / 32)             // 1563

typedef __attribute__((ext_vector_type(8))) short short8;
typedef __attribute__((ext_vector_type(4))) short short4v;
typedef __attribute__((ext_vector_type(4))) float f32x4;
typedef __attribute__((ext_vector_type(2))) float f32x2;

__device__ __forceinline__ float lrelu(float x) { return fmaxf(x, 0.2f * x); }

__device__ __forceinline__ unsigned short f2bf(float f) {
  unsigned int u = __float_as_uint(f);
  u += 0x7fffu + ((u >> 16) & 1u);  // RNE
  return (unsigned short)(u >> 16);
}
__device__ __forceinline__ float bfhi(unsigned int dw) { return __uint_as_float(dw & 0xffff0000u); }
__device__ __forceinline__ float bflo(unsigned int dw) { return __uint_as_float(dw << 16); }
__device__ __forceinline__ float elu(float x) { return x > 0.f ? x : __expf(x) - 1.f; }

__device__ __forceinline__ unsigned char f2fp8(float v) {
  return (unsigned char)(__builtin_amdgcn_cvt_pk_fp8_f32(v, v, 0, false) & 0xFF);
}

// ================= k_prep: wprep (blocks 0..69) || binA (blocks 70..460) =================
__global__ __launch_bounds__(256) void k_prep(const float* __restrict__ W1,
                                              const float* __restrict__ W2,
                                              unsigned short* __restrict__ W1b,
                                              unsigned short* __restrict__ W2b,
                                              const int* __restrict__ esrc,
                                              const int* __restrict__ edst,
                                              const float* __restrict__ ew,
                                              int* __restrict__ bktCnt,
                                              uint2* __restrict__ bSrcEw,
                                              unsigned short* __restrict__ bDst) {
  __shared__ __align__(16) char sm[46080];
  const int t = threadIdx.x;

  if (blockIdx.x < NB_PREP) {
    // ---- weight prepass ----
    int i = blockIdx.x * 256 + t;
    if (i < 16384) {  // W1: 16384 float4s
      float4 v = ((const float4*)W1)[i];
      short4v b;
      b[0] = (short)f2bf(v.x); b[1] = (short)f2bf(v.y);
      b[2] = (short)f2bf(v.z); b[3] = (short)f2bf(v.w);
      *(short4v*)&W1b[(size_t)i * 4] = b;
    } else if (i < 16384 + 1536) {  // W2b: 48 rows x 32 float4s (pad rows 40..47 with 0)
      int j = i - 16384;
      int col = j >> 5, q = j & 31;
      short4v b = {0, 0, 0, 0};
      if (col < 40) {
        float4 v = ((const float4*)W2)[col * 32 + q];
        b[0] = (short)f2bf(v.x); b[1] = (short)f2bf(v.y);
        b[2] = (short)f2bf(v.z); b[3] = (short)f2bf(v.w);
      }
      *(short4v*)&W2b[(size_t)col * 128 + q * 4] = b;
    }
    return;
  }

  // ---- binA: bucket-bin a 4096-edge tile ----
  int* cnt = (int*)sm;                       // 196 (pad 1024)
  int* scn = (int*)(sm + 1024);
  int* gbase = (int*)(sm + 2048);
  int* cur = (int*)(sm + 3072);
  int* tmp = (int*)(sm + 4096);              // 256
  uint2* stSE = (uint2*)(sm + 5120);         // 4096*8 = 32768
  unsigned short* stD = (unsigned short*)(sm + 37888);  // 8192
  const int e0 = (blockIdx.x - NB_PREP) * TILE;

  for (int b = t; b < NB; b += 256) cnt[b] = 0;
  __syncthreads();

  unsigned int sd[16];
  float wv[16];
#pragma unroll
  for (int u = 0; u < 16; ++u) {
    int e = e0 + t + 256 * u;
    if (e < NE) {
      unsigned int s = (unsigned int)esrc[e];
      unsigned int d = (unsigned int)edst[e];
      sd[u] = s | (d << 16);
      wv[u] = ew[e];
      atomicAdd(&cnt[d >> 8], 1);
    } else {
      sd[u] = 0xFFFFFFFFu;
    }
  }
  __syncthreads();

  int v = (t < NB) ? cnt[t] : 0;
  tmp[t] = v;
  __syncthreads();
  for (int off = 1; off < 256; off <<= 1) {
    int a = (t >= off) ? tmp[t - off] : 0;
    __syncthreads();
    tmp[t] += a;
    __syncthreads();
  }
  if (t < NB) {
    scn[t] = tmp[t] - v;
    cur[t] = tmp[t] - v;
    gbase[t] = atomicAdd(&bktCnt[t], v);
  }
  __syncthreads();

#pragma unroll
  for (int u = 0; u < 16; ++u) {
    if (sd[u] != 0xFFFFFFFFu) {
      unsigned int d = sd[u] >> 16;
      int p = atomicAdd(&cur[d >> 8], 1);
      stSE[p] = make_uint2(sd[u] & 0xFFFFu, __float_as_uint(wv[u]));
      stD[p] = (unsigned short)d;
    }
  }
  __syncthreads();

  int tot = NE - e0;
  if (tot > TILE) tot = TILE;
  for (int k = t; k < tot; k += 256) {
    int d = stD[k];
    int b = d >> 8;
    int idx = gbase[b] + (k - scn[b]);
    bSrcEw[(size_t)b * BCAP + idx] = stSE[k];
    bDst[(size_t)b * BCAP + idx] = (unsigned short)d;
  }
}

// ====== k_fuse2: fillB (blocks 0..195, inline bucket-prefix) || gemm1 (blocks 196..) ======
// gemm1: BM=32, BK=64, double-buffered LDS, depth-2 register prefetch, ONE barrier/chunk
__global__ __launch_bounds__(256) void k_fuse2(const int* __restrict__ bktCnt,
                                               const uint2* __restrict__ bSrcEw,
                                               const unsigned short* __restrict__ bDst,
                                               const float* __restrict__ ew,
                                               int* __restrict__ rs,
                                               uint2* __restrict__ edge,
                                               const float* __restrict__ x,
                                               const unsigned short* __restrict__ W1b,
                                               const float* __restrict__ attl,
                                               const float* __restrict__ attr,
                                               unsigned int* __restrict__ h1f32,
                                               float* __restrict__ al,
                                               float* __restrict__ ar) {
  __shared__ __align__(16) char sm[50176];
  const int t = threadIdx.x;

  if (blockIdx.x < NB) {
    // ---------------- fillB path ----------------
    int* cnt = (int*)sm;               // 256
    int* cur = (int*)(sm + 1024);      // 256
    int* tmp = (int*)(sm + 2048);      // 256
    int* bpre = (int*)(sm + 3072);     // 256
    int* sGb = (int*)(sm + 4096);
    const int b = blockIdx.x;
    const int n0 = b * 256;
    const int nNodes = (n0 + 256 <= NN) ? 256 : (NN - n0);

    // global bucket prefix, computed per block
    int bc = (t < NB) ? bktCnt[t] : 0;
    int nInB = 0;
    if (t < NB) nInB = (t == NB - 1) ? (NN - (NB - 1) * 256) : 256;
    int pv = bc + nInB;
    bpre[t] = pv;
    __syncthreads();
    for (int off = 1; off < 256; off <<= 1) {
      int a = (t >= off) ? bpre[t - off] : 0;
      __syncthreads();
      bpre[t] += a;
      __syncthreads();
    }
    if (t == b) *sGb = bpre[t] - pv;  // exclusive prefix at b
    if (t == 0 && b == 0) rs[NN] = NT;
    __syncthreads();
    const int gb = *sGb;
    const int cE = bktCnt[b];

    cnt[t] = 0;
    __syncthreads();
    for (int k = t; k < cE; k += 256) atomicAdd(&cnt[bDst[(size_t)b * BCAP + k] & 255], 1);
    __syncthreads();

    int v = (t < nNodes) ? cnt[t] + 1 : 0;  // +1 self loop
    tmp[t] = v;
    __syncthreads();
    for (int off = 1; off < 256; off <<= 1) {
      int a = (t >= off) ? tmp[t - off] : 0;
      __syncthreads();
      tmp[t] += a;
      __syncthreads();
    }
    int off_ = tmp[t] - v;  // exclusive
    if (t < nNodes) {
      rs[n0 + t] = gb + off_;
      cur[t] = off_ + 1;  // slot 0 = self loop
      edge[(size_t)gb + off_] = make_uint2((unsigned int)(n0 + t), __float_as_uint(ew[NE + n0 + t]));
    }
    __syncthreads();

    for (int k = t; k < cE; k += 256) {
      uint2 se = bSrcEw[(size_t)b * BCAP + k];
      int d = bDst[(size_t)b * BCAP + k] & 255;
      int p = atomicAdd(&cur[d], 1);
      edge[(size_t)gb + p] = se;  // XCD-local window
    }
    return;
  }

  // ---------------- gemm1 path: BK=64 dbuf + depth-2 register prefetch ----------------
  unsigned short* As0 = (unsigned short*)sm;            // 4608 B
  unsigned short* As1 = (unsigned short*)(sm + 4608);   // 4608 B
  unsigned short* Bs0 = (unsigned short*)(sm + 9216);   // 18432 B
  unsigned short* Bs1 = (unsigned short*)(sm + 27648);  // 18432 B
  unsigned int* pk32 = (unsigned int*)(sm + 46080);     // 4096 B
  const int w = t >> 6, lane = t & 63;
  const int g16 = lane >> 4, r16 = lane & 15;
  const int m0 = (blockIdx.x - NB) * 32;
  const int r0 = (w & 1) * 16;
  const int c0 = (w >> 1) * 64;
  const int row0 = t >> 4, k40 = (t & 15) << 2;   // A staging: rows row0, row0+16
  const int bcol = t >> 3, bk8 = (t & 7) << 3;    // B staging: cols bcol..+96

  const int nA0 = m0 + row0, nA1 = m0 + row0 + 16;
  const bool vA0 = nA0 < NN, vA1 = nA1 < NN;

  // two prefetch register sets (set for chunk c = set[c&1])
  float4 av0_0, av1_0, av0_1, av1_1;
  short8 bvr_0[4], bvr_1[4];

  // prologue: load chunk0 -> set0; write set0 -> buf0; issue chunk1 -> set1; barrier
  av0_0 = vA0 ? *(const float4*)&x[(size_t)nA0 * NF + k40] : make_float4(0.f, 0.f, 0.f, 0.f);
  av1_0 = vA1 ? *(const float4*)&x[(size_t)nA1 * NF + k40] : make_float4(0.f, 0.f, 0.f, 0.f);
#pragma unroll
  for (int i = 0; i < 4; ++i)
    bvr_0[i] = *(const short8*)&W1b[(size_t)(bcol + 32 * i) * NF + bk8];
  {
    short4v b0, b1;
    b0[0] = (short)f2bf(av0_0.x); b0[1] = (short)f2bf(av0_0.y);
    b0[2] = (short)f2bf(av0_0.z); b0[3] = (short)f2bf(av0_0.w);
    b1[0] = (short)f2bf(av1_0.x); b1[1] = (short)f2bf(av1_0.y);
    b1[2] = (short)f2bf(av1_0.z); b1[3] = (short)f2bf(av1_0.w);
    *(short4v*)&As0[row0 * 72 + k40] = b0;
    *(short4v*)&As0[(row0 + 16) * 72 + k40] = b1;
#pragma unroll
    for (int i = 0; i < 4; ++i)
      *(short8*)&Bs0[(bcol + 32 * i) * 72 + bk8] = bvr_0[i];
  }
  // issue chunk1 loads -> set1
  av0_1 = vA0 ? *(const float4*)&x[(size_t)nA0 * NF + 64 + k40] : make_float4(0.f, 0.f, 0.f, 0.f);
  av1_1 = vA1 ? *(const float4*)&x[(size_t)nA1 * NF + 64 + k40] : make_float4(0.f, 0.f, 0.f, 0.f);
#pragma unroll
  for (int i = 0; i < 4; ++i)
    bvr_1[i] = *(const short8*)&W1b[(size_t)(bcol + 32 * i) * NF + 64 + bk8];
  __syncthreads();

  f32x4 acc[4];
#pragma unroll
  for (int b = 0; b < 4; ++b) acc[b] = (f32x4){0.f, 0.f, 0.f, 0.f};

#pragma unroll
  for (int kc = 0; kc < 8; ++kc) {
    unsigned short* Ac = (kc & 1) ? As1 : As0;
    unsigned short* Bc = (kc & 1) ? Bs1 : Bs0;
    unsigned short* An = (kc & 1) ? As0 : As1;
    unsigned short* Bn = (kc & 1) ? Bs0 : Bs1;

    // (1) issue loads for chunk kc+2 into set[kc&1] (just freed: its data is in LDS)
    if (kc < 6) {
      int kn = (kc + 2) * 64;
      if (kc & 1) {
        av0_1 = vA0 ? *(const float4*)&x[(size_t)nA0 * NF + kn + k40] : make_float4(0.f, 0.f, 0.f, 0.f);
        av1_1 = vA1 ? *(const float4*)&x[(size_t)nA1 * NF + kn + k40] : make_float4(0.f, 0.f, 0.f, 0.f);
#pragma unroll
        for (int i = 0; i < 4; ++i)
          bvr_1[i] = *(const short8*)&W1b[(size_t)(bcol + 32 * i) * NF + kn + bk8];
      } else {
        av0_0 = vA0 ? *(const float4*)&x[(size_t)nA0 * NF + kn + k40] : make_float4(0.f, 0.f, 0.f, 0.f);
        av1_0 = vA1 ? *(const float4*)&x[(size_t)nA1 * NF + kn + k40] : make_float4(0.f, 0.f, 0.f, 0.f);
#pragma unroll
        for (int i = 0; i < 4; ++i)
          bvr_0[i] = *(const short8*)&W1b[(size_t)(bcol + 32 * i) * NF + kn + bk8];
      }
    }

    // (2) current-chunk fragments from LDS
    short8 afr[2], bfr[4][2];
#pragma unroll
    for (int ks = 0; ks < 2; ++ks)
      afr[ks] = *(const short8*)&Ac[(r0 + r16) * 72 + ks * 32 + g16 * 8];
#pragma unroll
    for (int nj = 0; nj < 4; ++nj)
#pragma unroll
      for (int ks = 0; ks < 2; ++ks)
        bfr[nj][ks] = *(const short8*)&Bc[(c0 + nj * 16 + r16) * 72 + ks * 32 + g16 * 8];

    // (3) write chunk kc+1 (loaded one full chunk ago -> latency covered) into other buffer
    if (kc < 7) {
      float4 a0 = (kc & 1) ? av0_0 : av0_1;
      float4 a1 = (kc & 1) ? av1_0 : av1_1;
      short4v b0, b1;
      b0[0] = (short)f2bf(a0.x); b0[1] = (short)f2bf(a0.y);
      b0[2] = (short)f2bf(a0.z); b0[3] = (short)f2bf(a0.w);
      b1[0] = (short)f2bf(a1.x); b1[1] = (short)f2bf(a1.y);
      b1[2] = (short)f2bf(a1.z); b1[3] = (short)f2bf(a1.w);
      *(short4v*)&An[row0 * 72 + k40] = b0;
      *(short4v*)&An[(row0 + 16) * 72 + k40] = b1;
      if (kc & 1) {
#pragma unroll
        for (int i = 0; i < 4; ++i)
          *(short8*)&Bn[(bcol + 32 * i) * 72 + bk8] = bvr_0[i];
      } else {
#pragma unroll
        for (int i = 0; i < 4; ++i)
          *(short8*)&Bn[(bcol + 32 * i) * 72 + bk8] = bvr_1[i];
      }
    }

    // (4) MFMA on current chunk
#pragma unroll
    for (int nj = 0; nj < 4; ++nj)
#pragma unroll
      for (int ks = 0; ks < 2; ++ks)
        acc[nj] = __builtin_amdgcn_mfma_f32_16x16x32_bf16(afr[ks], bfr[nj][ks], acc[nj], 0, 0, 0);

    // (5) ONE barrier per chunk
    if (kc < 7) __syncthreads();
  }

  // fp8-pack into LDS
  unsigned char* pkb = (unsigned char*)pk32;
  __syncthreads();
#pragma unroll
  for (int nj = 0; nj < 4; ++nj)
#pragma unroll
    for (int r = 0; r < 4; ++r)
      pkb[(r0 + g16 * 4 + r) * 128 + c0 + nj * 16 + r16] = f2fp8(acc[nj][r]);
  __syncthreads();

  {
    int row = t >> 3, q = t & 7;
    int n = m0 + row;
    if (n < NN) ((uint4*)h1f32)[(size_t)n * 8 + q] = ((const uint4*)pk32)[row * 8 + q];
  }
  {
    int row = t >> 3, h = t & 7;
    int n = m0 + row;
    if (n < NN) {
      float a = 0.f, b = 0.f;
#pragma unroll
      for (int c = 0; c < 4; ++c) {
        unsigned int u = pk32[row * 32 + h * 4 + c];
        f32x2 lo = __builtin_amdgcn_cvt_pk_f32_fp8((int)u, false);
        f32x2 hi = __builtin_amdgcn_cvt_pk_f32_fp8((int)u, true);
        int f0 = h * 16 + 4 * c;
        a = fmaf(lo[0], attl[f0], a);
        a = fmaf(lo[1], attl[f0 + 1], a);
        a = fmaf(hi[0], attl[f0 + 2], a);
        a = fmaf(hi[1], attl[f0 + 3], a);
        b = fmaf(lo[0], attr[f0], b);
        b = fmaf(lo[1], attr[f0 + 1], b);
        b = fmaf(hi[0], attr[f0 + 2], b);
        b = fmaf(hi[1], attr[f0 + 3], b);
      }
      al[n * 8 + h] = a;
      ar[n * 8 + h] = b;
    }
  }
}

// ---- layer-1 aggregation: 2 nodes/wave, 12-deep batch, plain exp, fp8 gather ----
__global__ __launch_bounds__(256) void k_agg1(const int* __restrict__ rs,
                                              const uint2* __restrict__ edge,
                                              const unsigned int* __restrict__ h1f32,
                                              const float* __restrict__ al,
                                              const float* __restrict__ ar,
                                              const float* __restrict__ b1,
                                              uint2* __restrict__ h1eb) {
  const int hl = threadIdx.x & 31;
  const int i = blockIdx.x * 8 + (threadIdx.x >> 5);
  if (i >= NN) return;
  const int base = rs[i], end = rs[i + 1];
  const int head = hl >> 2;
  const float arh = ar[i * 8 + head];
  float s0 = 0.f, s1 = 0.f;
  float a0 = 0.f, a1 = 0.f, a2 = 0.f, a3 = 0.f;
  float c0 = 0.f, c1 = 0.f, c2 = 0.f, c3 = 0.f;

  int e = base;
  for (; e + 12 <= end; e += 12) {
    uint2 ce[12];
    float lgs[12];
    unsigned int hvs[12];
#pragma unroll
    for (int u = 0; u < 12; ++u) ce[u] = edge[e + u];
#pragma unroll
    for (int u = 0; u < 12; ++u) lgs[u] = al[(int)ce[u].x * 8 + head];
#pragma unroll
    for (int u = 0; u < 12; ++u) hvs[u] = h1f32[(size_t)ce[u].x * 32 + hl];
#pragma unroll
    for (int u = 0; u < 12; ++u) {
      float q = __expf(lrelu(lgs[u] + arh));
      float pw = q * __uint_as_float(ce[u].y);
      f32x2 lo = __builtin_amdgcn_cvt_pk_f32_fp8((int)hvs[u], false);
      f32x2 hi = __builtin_amdgcn_cvt_pk_f32_fp8((int)hvs[u], true);
      if (u & 1) {
        s1 += q;
        c0 = fmaf(pw, lo[0], c0);
        c1 = fmaf(pw, lo[1], c1);
        c2 = fmaf(pw, hi[0], c2);
        c3 = fmaf(pw, hi[1], c3);
      } else {
        s0 += q;
        a0 = fmaf(pw, lo[0], a0);
        a1 = fmaf(pw, lo[1], a1);
        a2 = fmaf(pw, hi[0], a2);
        a3 = fmaf(pw, hi[1], a3);
      }
    }
  }
  for (; e + 4 <= end; e += 4) {
    uint2 ce[4];
    float lgs[4];
    unsigned int hvs[4];
#pragma unroll
    for (int u = 0; u < 4; ++u) ce[u] = edge[e + u];
#pragma unroll
    for (int u = 0; u < 4; ++u) lgs[u] = al[(int)ce[u].x * 8 + head];
#pragma unroll
    for (int u = 0; u < 4; ++u) hvs[u] = h1f32[(size_t)ce[u].x * 32 + hl];
#pragma unroll
    for (int u = 0; u < 4; ++u) {
      float q = __expf(lrelu(lgs[u] + arh));
      float pw = q * __uint_as_float(ce[u].y);
      f32x2 lo = __builtin_amdgcn_cvt_pk_f32_fp8((int)hvs[u], false);
      f32x2 hi = __builtin_amdgcn_cvt_pk_f32_fp8((int)hvs[u], true);
      if (u & 1) {
        s1 += q;
        c0 = fmaf(pw, lo[0], c0);
        c1 = fmaf(pw, lo[1], c1);
        c2 = fmaf(pw, hi[0], c2);
        c3 = fmaf(pw, hi[1], c3);
      } else {
        s0 += q;
        a0 = fmaf(pw, lo[0], a0);
        a1 = fmaf(pw, lo[1], a1);
        a2 = fmaf(pw, hi[0], a2);
        a3 = fmaf(pw, hi[1], a3);
      }
    }
  }
  for (; e < end; ++e) {
    uint2 ce = edge[e];
    int j = (int)ce.x;
    float q = __expf(lrelu(al[j * 8 + head] + arh));
    unsigned int hv = h1f32[(size_t)j * 32 + hl];
    float pw = q * __uint_as_float(ce.y);
    f32x2 lo = __builtin_amdgcn_cvt_pk_f32_fp8((int)hv, false);
    f32x2 hi = __builtin_amdgcn_cvt_pk_f32_fp8((int)hv, true);
    s0 += q;
    a0 = fmaf(pw, lo[0], a0);
    a1 = fmaf(pw, lo[1], a1);
    a2 = fmaf(pw, hi[0], a2);
    a3 = fmaf(pw, hi[1], a3);
  }
  float inv = 1.f / (s0 + s1);
  float4 bias = *(const float4*)&b1[4 * hl];
  float o0 = elu(fmaf(a0 + c0, inv, bias.x));
  float o1 = elu(fmaf(a1 + c1, inv, bias.y));
  float o2 = elu(fmaf(a2 + c2, inv, bias.z));
  float o3 = elu(fmaf(a3 + c3, inv, bias.w));
  uint2 pk;
  pk.x = (unsigned int)f2bf(o0) | ((unsigned int)f2bf(o1) << 16);
  pk.y = (unsigned int)f2bf(o2) | ((unsigned int)f2bf(o3) << 16);
  h1eb[(size_t)i * 32 + hl] = pk;
}

// ---- GEMM2 (MFMA bf16, one K-shot): hp2f[N][40] = fp8(h1e @ W2^T); fused alr2 ----
__global__ __launch_bounds__(256) void k_gemm2(const uint4* __restrict__ h1eb4,
                                               const unsigned short* __restrict__ W2b,
                                               const float* __restrict__ attl,
                                               const float* __restrict__ attr,
                                               unsigned int* __restrict__ hp2f32,
                                               float* __restrict__ al,
                                               float* __restrict__ ar) {
  __shared__ unsigned short As[64 * 136];
  __shared__ unsigned short Bs[48 * 136];
  __shared__ unsigned int pkd[64 * 10];
  const int t = threadIdx.x;
  const int w = t >> 6, lane = t & 63;
  const int g16 = lane >> 4, r16 = lane & 15;
  const int n0 = blockIdx.x * 64;

#pragma unroll
  for (int i = 0; i < 4; ++i) {
    int idx = t + 256 * i;
    int row = idx >> 4, q = idx & 15;
    int n = n0 + row;
    uint4 v = make_uint4(0u, 0u, 0u, 0u);
    if (n < NN) v = h1eb4[(size_t)n * 16 + q];
    *(uint4*)&As[row * 136 + q * 8] = v;
  }
#pragma unroll
  for (int i = 0; i < 3; ++i) {
    int idx = t + 256 * i;
    int col = idx >> 4, q = idx & 15;
    *(uint4*)&Bs[col * 136 + q * 8] = ((const uint4*)W2b)[col * 16 + q];
  }
  __syncthreads();

  f32x4 acc[3];
#pragma unroll
  for (int b = 0; b < 3; ++b) acc[b] = (f32x4){0.f, 0.f, 0.f, 0.f};
  short8 afr[4];
#pragma unroll
  for (int kc = 0; kc < 4; ++kc)
    afr[kc] = *(const short8*)&As[(w * 16 + r16) * 136 + kc * 32 + g16 * 8];
#pragma unroll
  for (int nt = 0; nt < 3; ++nt) {
#pragma unroll
    for (int kc = 0; kc < 4; ++kc) {
      short8 bfr = *(const short8*)&Bs[(nt * 16 + r16) * 136 + kc * 32 + g16 * 8];
      acc[nt] = __builtin_amdgcn_mfma_f32_16x16x32_bf16(afr[kc], bfr, acc[nt], 0, 0, 0);
    }
  }

  unsigned char* pkb = (unsigned char*)pkd;
  __syncthreads();
#pragma unroll
  for (int nt = 0; nt < 3; ++nt) {
    int col = nt * 16 + r16;
    if (col < 40) {
#pragma unroll
      for (int r = 0; r < 4; ++r)
        pkb[(w * 16 + g16 * 4 + r) * 40 + col] = f2fp8(acc[nt][r]);
    }
  }
  __syncthreads();

  for (int idx = t; idx < 640; idx += 256) {
    int row = idx / 10, q = idx - row * 10;
    int n = n0 + row;
    if (n < NN) hp2f32[(size_t)n * 10 + q] = pkd[row * 10 + q];
  }
  if (t < 64) {
    int n = n0 + t;
    if (n < NN) {
      float a = 0.f, b = 0.f;
#pragma unroll
      for (int c = 0; c < 10; ++c) {
        unsigned int u = pkd[t * 10 + c];
        f32x2 lo = __builtin_amdgcn_cvt_pk_f32_fp8((int)u, false);
        f32x2 hi = __builtin_amdgcn_cvt_pk_f32_fp8((int)u, true);
        a = fmaf(lo[0], attl[4 * c], a);
        a = fmaf(lo[1], attl[4 * c + 1], a);
        a = fmaf(hi[0], attl[4 * c + 2], a);
        a = fmaf(hi[1], attl[4 * c + 3], a);
        b = fmaf(lo[0], attr[4 * c], b);
        b = fmaf(lo[1], attr[4 * c + 1], b);
        b = fmaf(hi[0], attr[4 * c + 2], b);
        b = fmaf(hi[1], attr[4 * c + 3], b);
      }
      al[n] = a;
      ar[n] = b;
    }
  }
}

// ---- layer-2 attention prepass: 2 nodes/wave; edge.y <- q*ew, sinv[i] = 1/sum(q) ----
__global__ __launch_bounds__(256) void k_qw2(const int* __restrict__ rs,
                                             uint2* __restrict__ edge,
                                             const float* __restrict__ al2,
                                             const float* __restrict__ ar2,
                                             float* __restrict__ sinv) {
  const int l = threadIdx.x & 31;
  const int i = blockIdx.x * 8 + (threadIdx.x >> 5);
  if (i >= NN) return;
  const int base = rs[i], end = rs[i + 1];
  const float ari = ar2[i];
  float s = 0.f;
  for (int e = base + l; e < end; e += 32) {
    uint2 ce = edge[e];
    float q = __expf(lrelu(al2[(int)ce.x] + ari));
    s += q;
    ((float*)&edge[e])[1] = q * __uint_as_float(ce.y);
  }
#pragma unroll
  for (int off = 1; off < 32; off <<= 1) s += __shfl_xor(s, off, 32);
  if (l == 0) sinv[i] = 1.f / s;
}

// ---- layer-2 aggregation + bias + log_softmax: 2 nodes/wave, 16-deep batch ----
__global__ __launch_bounds__(256) void k_agg2(const int* __restrict__ rs,
                                              const uint2* __restrict__ edge,
                                              const unsigned short* __restrict__ hp2f16,
                                              const float* __restrict__ sinv,
                                              const float* __restrict__ b2,
                                              float* __restrict__ out) {
  const int hl = threadIdx.x & 31;
  const int i = blockIdx.x * 8 + (threadIdx.x >> 5);
  if (i >= NN) return;
  const int base = rs[i], end = rs[i + 1];
  float a0 = 0.f, a1 = 0.f, c0 = 0.f, c1 = 0.f;

  int e = base;
  for (; e + 16 <= end; e += 16) {
    uint2 ce[16];
#pragma unroll
    for (int u = 0; u < 16; ++u) ce[u] = edge[e + u];
    unsigned int hv[16];
#pragma unroll
    for (int u = 0; u < 16; ++u)
      hv[u] = (hl < 20) ? (unsigned int)hp2f16[(size_t)ce[u].x * 20 + hl] : 0u;
#pragma unroll
    for (int u = 0; u < 16; ++u) {
      float p = __uint_as_float(ce[u].y);
      f32x2 v = __builtin_amdgcn_cvt_pk_f32_fp8((int)hv[u], false);
      if (u & 1) {
        c0 = fmaf(p, v[0], c0);
        c1 = fmaf(p, v[1], c1);
      } else {
        a0 = fmaf(p, v[0], a0);
        a1 = fmaf(p, v[1], a1);
      }
    }
  }
  for (; e + 4 <= end; e += 4) {
    uint2 ce[4];
#pragma unroll
    for (int u = 0; u < 4; ++u) ce[u] = edge[e + u];
    unsigned int hv[4];
#pragma unroll
    for (int u = 0; u < 4; ++u)
      hv[u] = (hl < 20) ? (unsigned int)hp2f16[(size_t)ce[u].x * 20 + hl] : 0u;
#pragma unroll
    for (int u = 0; u < 4; ++u) {
      float p = __uint_as_float(ce[u].y);
      f32x2 v = __builtin_amdgcn_cvt_pk_f32_fp8((int)hv[u], false);
      if (u & 1) {
        c0 = fmaf(p, v[0], c0);
        c1 = fmaf(p, v[1], c1);
      } else {
        a0 = fmaf(p, v[0], a0);
        a1 = fmaf(p, v[1], a1);
      }
    }
  }
  for (; e < end; ++e) {
    uint2 ce = edge[e];
    unsigned int hv = (hl < 20) ? (unsigned int)hp2f16[(size_t)ce.x * 20 + hl] : 0u;
    float p = __uint_as_float(ce.y);
    f32x2 v = __builtin_amdgcn_cvt_pk_f32_fp8((int)hv, false);
    a0 = fmaf(p, v[0], a0);
    a1 = fmaf(p, v[1], a1);
  }
  a0 += c0;
  a1 += c1;
  float inv = sinv[i];
  float v0 = -1e30f, v1 = -1e30f;
  if (hl < 20) {
    v0 = fmaf(a0, inv, b2[2 * hl]);
    v1 = fmaf(a1, inv, b2[2 * hl + 1]);
  }
  float mx = fmaxf(v0, v1);
#pragma unroll
  for (int off = 1; off < 32; off <<= 1) mx = fmaxf(mx, __shfl_xor(mx, off, 32));
  float se = (hl < 20) ? __expf(v0 - mx) + __expf(v1 - mx) : 0.f;
#pragma unroll
  for (int off = 1; off < 32; off <<= 1) se += __shfl_xor(se, off, 32);
  if (hl < 20) {
    float ls = mx + __logf(se);
    ((float2*)(out + (size_t)i * 40))[hl] = make_float2(v0 - ls, v1 - ls);
  }
}

extern "C" void kernel_launch(void* const* d_in, const int* in_sizes, int n_in,
                              void* d_out, int out_size, void* d_ws, size_t ws_size,
                              hipStream_t stream) {
  const float* x     = (const float*)d_in[0];
  const int*   esrc  = (const int*)d_in[1];
  const int*   edst  = (const int*)d_in[2];
  const float* ew    = (const float*)d_in[3];
  const float* W1    = (const float*)d_in[4];
  const float* attl1 = (const float*)d_in[5];
  const float* attr1 = (const float*)d_in[6];
  const float* b1    = (const float*)d_in[7];
  const float* W2    = (const float*)d_in[8];
  const float* attl2 = (const float*)d_in[9];
  const float* attr2 = (const float*)d_in[10];
  const float* b2    = (const float*)d_in[11];
  float* out = (float*)d_out;

  char* w = (char*)d_ws;
  auto take = [&](size_t bytes) {
    char* p = w;
    w += (bytes + 255) & ~(size_t)255;
    return p;
  };
  unsigned int* h1f  = (unsigned int*)take((size_t)NN * F1);       // fp8 table, 6.4 MB
  unsigned int* h1eb = (unsigned int*)take((size_t)NN * 64 * 4);   // bf16, 12.8 MB
  float* al1 = (float*)take((size_t)NN * NH * 4);
  float* ar1 = (float*)take((size_t)NN * NH * 4);
  unsigned int* hp2f = (unsigned int*)take((size_t)NN * 40);       // fp8 table, 2 MB
  float* al2 = (float*)take((size_t)NN * 4);
  float* ar2 = (float*)take((size_t)NN * 4);
  float* sinv = (float*)take((size_t)NN * 4);
  int*   rs  = (int*)take((size_t)(NN + 1) * 4);
  uint2* edge = (uint2*)take((size_t)NT * 8);
  unsigned short* W1b = (unsigned short*)take((size_t)F1 * NF * 2); // 128 KB bf16 W1
  unsigned short* W2b = (unsigned short*)take((size_t)48 * 128 * 2); // 12 KB bf16 W2 (pad 48)
  int* bktCnt = (int*)take(NB * 4);
  // DEDICATED staging (no aliasing! fillB runs concurrently with gemm1 which writes h1f/al1)
  uint2* bSrcEw = (uint2*)take((size_t)NB * BCAP * 8);              // 16.06 MB
  unsigned short* bDst = (unsigned short*)take((size_t)NB * BCAP * 2);  // 4.01 MB

  hipMemsetAsync(bktCnt, 0, NB * 4, stream);
  // wprep || binA
  k_prep<<<NB_PREP + NB_BINA, 256, 0, stream>>>(W1, W2, W1b, W2b,
                                                esrc, edst, ew, bktCnt, bSrcEw, bDst);
  // fillB (with inline bucket scan) || gemm1(+alr1, depth-2 pipelined)
  k_fuse2<<<NB + NB_G1, 256, 0, stream>>>(bktCnt, bSrcEw, bDst, ew, rs, edge,
                                          x, W1b, attl1, attr1, h1f, al1, ar1);
  // layer-1 aggregation
  k_agg1<<<(NN + 7) / 8, 256, 0, stream>>>(rs, edge, h1f, al1, ar1, b1, (uint2*)h1eb);
  // layer 2
  k_gemm2<<<(NN + 63) / 64, 256, 0, stream>>>((const uint4*)h1eb, W2b, attl2, attr2,
                                              hp2f, al2, ar2);
  k_qw2<<<(NN + 7) / 8, 256, 0, stream>>>(rs, edge, al2, ar2, sinv);
  k_agg2<<<(NN + 7) / 8, 256, 0, stream>>>(rs, edge, (const unsigned short*)hp2f, sinv, b2, out);
}